// Round 1
// baseline (1008.815 us; speedup 1.0000x reference)
//
#include <hip/hip_runtime.h>
#include <hip/hip_bf16.h>
#include <cstddef>

// Problem constants (match reference)
#define B_   128
#define L_   128
#define H_   1024
#define V_   50000
#define INDIM 1088   // H + 32 + 32

// ---------------------------------------------------------------------------
// Kernel 1: build GRU input x[b, 0:1088] = [emb[idx], sound_emb[snd], num_emb[num]]
// ---------------------------------------------------------------------------
__global__ __launch_bounds__(256) void build_x_kernel(
    const int* __restrict__ seq, const int* __restrict__ c2n,
    const int* __restrict__ c2f, const float* __restrict__ emb,
    const float* __restrict__ semb, const float* __restrict__ nemb,
    float* __restrict__ x)
{
    const int b = blockIdx.x;
    const int t = threadIdx.x;
    const int idx = seq[b];
    float* xb = x + (size_t)b * INDIM;
    const float* eb = emb + (size_t)idx * H_;
    // 1024 floats = 256 float4, one per thread
    ((float4*)xb)[t] = ((const float4*)eb)[t];
    if (t < 32) {
        const int sid = c2f[idx];
        const int nid = c2n[idx];
        xb[1024 + t] = semb[sid * 32 + t];
        xb[1056 + t] = nemb[nid * 32 + t];
    }
}

// ---------------------------------------------------------------------------
// Generic f32 GEMM: C[128, N] = A[128, K] * W^T (+bias)(+tanh)
//   WT=true : W is [N, K] row-major (PyTorch Linear weight) -> C = A @ W.T
//   WT=false: W is [K, N] row-major                         -> C = A @ W
// Tile: 128 (all rows) x 64 cols, K-chunk 32. 256 threads, 4x8 per thread.
// ---------------------------------------------------------------------------
template<bool WT, bool TANH>
__global__ __launch_bounds__(256) void gemm128_kernel(
    const float* __restrict__ A, int lda,
    const float* __restrict__ W, int ldw,
    const float* __restrict__ bias,
    float* __restrict__ C, int ldc,
    int N, int K)
{
    __shared__ float As[32][132];  // [k][b], padded (528B row = 33*16 -> b128 ok)
    __shared__ float Ws[32][68];   // [k][n], padded (272B row = 17*16)

    const int t  = threadIdx.x;
    const int tb = t & 31;   // b-group: rows 4*tb .. 4*tb+3
    const int tg = t >> 5;   // n-group: cols 8*tg .. 8*tg+7
    const int n0 = blockIdx.x * 64;

    float acc[4][8];
#pragma unroll
    for (int i = 0; i < 4; i++)
#pragma unroll
        for (int j = 0; j < 8; j++) acc[i][j] = 0.f;

    for (int k0 = 0; k0 < K; k0 += 32) {
        // stage A chunk (transpose to [k][b])
        {
            const int kk = (t & 7) * 4;
            const int b0 = t >> 3;
            for (int bb = b0; bb < 128; bb += 32) {
                float4 v = *(const float4*)&A[(size_t)bb * lda + k0 + kk];
                As[kk + 0][bb] = v.x; As[kk + 1][bb] = v.y;
                As[kk + 2][bb] = v.z; As[kk + 3][bb] = v.w;
            }
        }
        // stage W chunk into [k][n]
        if (WT) {
            const int kk = (t & 7) * 4;
            const int nb = t >> 3;
            for (int nn = nb; nn < 64; nn += 32) {
                const int gn = n0 + nn;
                float4 v = make_float4(0.f, 0.f, 0.f, 0.f);
                if (gn < N) v = *(const float4*)&W[(size_t)gn * ldw + k0 + kk];
                Ws[kk + 0][nn] = v.x; Ws[kk + 1][nn] = v.y;
                Ws[kk + 2][nn] = v.z; Ws[kk + 3][nn] = v.w;
            }
        } else {
            const int nn = (t & 15) * 4;
            const int kb = t >> 4;
            for (int k2 = kb; k2 < 32; k2 += 16) {
                // NT path only used with N % 64 == 0 (no guard needed)
                float4 v = *(const float4*)&W[(size_t)(k0 + k2) * ldw + n0 + nn];
                *(float4*)&Ws[k2][nn] = v;
            }
        }
        __syncthreads();

#pragma unroll
        for (int k = 0; k < 32; k++) {
            float4 a  = *(const float4*)&As[k][4 * tb];
            float4 w0 = *(const float4*)&Ws[k][8 * tg];
            float4 w1 = *(const float4*)&Ws[k][8 * tg + 4];
            const float av[4] = {a.x, a.y, a.z, a.w};
            const float wv[8] = {w0.x, w0.y, w0.z, w0.w, w1.x, w1.y, w1.z, w1.w};
#pragma unroll
            for (int i = 0; i < 4; i++)
#pragma unroll
                for (int j = 0; j < 8; j++) acc[i][j] += av[i] * wv[j];
        }
        __syncthreads();
    }

    // epilogue
#pragma unroll
    for (int i = 0; i < 4; i++) {
        const int b = 4 * tb + i;
#pragma unroll
        for (int j = 0; j < 8; j++) {
            const int n = n0 + 8 * tg + j;
            if (n < N) {
                float v = acc[i][j] + (bias ? bias[n] : 0.f);
                if (TANH) v = tanhf(v);
                C[(size_t)b * ldc + n] = v;
            }
        }
    }
}

// ---------------------------------------------------------------------------
// Kernel: GRU gates (r,z,n order). Writes h_new into cat[:, :1024] and d_out hidden.
// ---------------------------------------------------------------------------
__global__ __launch_bounds__(256) void gru_gates_kernel(
    const float* __restrict__ gi, const float* __restrict__ gh,
    const float* __restrict__ h_prev,
    float* __restrict__ cat, float* __restrict__ hid_out)
{
    const int id = blockIdx.x * 256 + threadIdx.x;   // 0 .. 131071
    const int b = id >> 10;
    const int j = id & 1023;
    const float ir = gi[(size_t)b * 3072 + j];
    const float iz = gi[(size_t)b * 3072 + 1024 + j];
    const float in_ = gi[(size_t)b * 3072 + 2048 + j];
    const float hr = gh[(size_t)b * 3072 + j];
    const float hz = gh[(size_t)b * 3072 + 1024 + j];
    const float hn = gh[(size_t)b * 3072 + 2048 + j];
    const float r = 1.f / (1.f + __expf(-(ir + hr)));
    const float z = 1.f / (1.f + __expf(-(iz + hz)));
    const float n = tanhf(in_ + r * hn);
    const float hp = h_prev[id];
    const float h = (1.f - z) * n + z * hp;
    cat[(size_t)b * 2048 + j] = h;
    hid_out[id] = h;
}

// ---------------------------------------------------------------------------
// Fused attention: energies -> softmax -> context, one block per b.
// energies[b,l] = q[b,:] . enc[l,b,:]   (b_attn dropped: softmax shift-invariant)
// ---------------------------------------------------------------------------
__global__ __launch_bounds__(256) void attn_kernel(
    const float* __restrict__ q,     // [128,1024] = h_new @ W_attn
    const float* __restrict__ enc,   // [L,B,H]
    float* __restrict__ cat,         // [128,2048]; write context to [:,1024:]
    float* __restrict__ attn_out)    // [B,L]
{
    const int b = blockIdx.x;
    const int t = threadIdx.x;
    const int lane = t & 63;
    const int wv = t >> 6;

    __shared__ float q_s[1024];
    __shared__ float e_s[128];
    __shared__ float red[4];

    *(float4*)&q_s[t * 4] = ((const float4*)(q + (size_t)b * 1024))[t];
    __syncthreads();

    const float* encb = enc + (size_t)b * H_;   // enc[l][b][h] = encb[l*131072 + h]

    // energies: wave wv handles l = wv*32 .. wv*32+31, 64-lane dot each
    for (int l0 = 0; l0 < 32; ++l0) {
        const int l = wv * 32 + l0;
        const float* er = encb + (size_t)l * (B_ * H_);
        float p = 0.f;
#pragma unroll
        for (int m = 0; m < 4; m++) {
            float4 ev = *(const float4*)&er[m * 256 + lane * 4];
            float4 qv = *(const float4*)&q_s[m * 256 + lane * 4];
            p += ev.x * qv.x + ev.y * qv.y + ev.z * qv.z + ev.w * qv.w;
        }
#pragma unroll
        for (int off = 32; off > 0; off >>= 1) p += __shfl_xor(p, off);
        if (lane == 0) e_s[l] = p;
    }
    __syncthreads();

    // softmax over 128 energies
    float e = (t < 128) ? e_s[t] : -INFINITY;
    float mx = e;
#pragma unroll
    for (int off = 32; off > 0; off >>= 1) mx = fmaxf(mx, __shfl_xor(mx, off));
    if (lane == 0) red[wv] = mx;
    __syncthreads();
    const float gm = fmaxf(fmaxf(red[0], red[1]), fmaxf(red[2], red[3]));
    __syncthreads();
    float ex = (t < 128) ? __expf(e - gm) : 0.f;
    float sm = ex;
#pragma unroll
    for (int off = 32; off > 0; off >>= 1) sm += __shfl_xor(sm, off);
    if (lane == 0) red[wv] = sm;
    __syncthreads();
    const float gs = red[0] + red[1] + red[2] + red[3];
    const float w = ex / gs;
    if (t < 128) {
        attn_out[(size_t)b * L_ + t] = w;
        e_s[t] = w;
    }
    __syncthreads();

    // context[b, j] = sum_l w[l] * enc[l,b,j]; thread owns 4 h's
    float4 c = make_float4(0.f, 0.f, 0.f, 0.f);
#pragma unroll 4
    for (int l = 0; l < 128; l++) {
        const float wl = e_s[l];
        float4 ev = *(const float4*)&encb[(size_t)l * (B_ * H_) + t * 4];
        c.x += wl * ev.x; c.y += wl * ev.y; c.z += wl * ev.z; c.w += wl * ev.w;
    }
    *(float4*)&cat[(size_t)b * 2048 + 1024 + t * 4] = c;
}

// ---------------------------------------------------------------------------
// Host launcher
// ---------------------------------------------------------------------------
extern "C" void kernel_launch(void* const* d_in, const int* in_sizes, int n_in,
                              void* d_out, int out_size, void* d_ws, size_t ws_size,
                              hipStream_t stream)
{
    const int*   seq    = (const int*)  d_in[0];
    const float* lh     = (const float*)d_in[1];   // [1,B,H]
    const float* enc    = (const float*)d_in[2];   // [L,B,H]
    const int*   c2n    = (const int*)  d_in[3];
    const int*   c2f    = (const int*)  d_in[4];
    const float* emb    = (const float*)d_in[5];
    const float* semb   = (const float*)d_in[6];
    const float* nemb   = (const float*)d_in[7];
    const float* W_ih   = (const float*)d_in[8];   // [3072,1088]
    const float* W_hh   = (const float*)d_in[9];   // [3072,1024]
    const float* b_ih   = (const float*)d_in[10];
    const float* b_hh   = (const float*)d_in[11];
    const float* W_attn = (const float*)d_in[12];  // [1024,1024] (k,h)
    // d_in[13] = b_attn: softmax shift-invariant -> unused (exact)
    const float* W_cat  = (const float*)d_in[14];  // [1024,2048]
    const float* b_cat  = (const float*)d_in[15];
    const float* W_out  = (const float*)d_in[16];  // [50000,1024]
    const float* b_out  = (const float*)d_in[17];

    float* out    = (float*)d_out;                       // [B,V]
    float* hidden = out + (size_t)B_ * V_;               // [1,B,H]
    float* attnw  = hidden + (size_t)B_ * H_;            // [B,1,L]

    // workspace layout (floats)
    float* ws  = (float*)d_ws;
    float* x   = ws;                       // B x 1088
    float* gi  = x   + (size_t)B_ * INDIM; // B x 3072
    float* gh  = gi  + (size_t)B_ * 3072;  // B x 3072
    float* cat = gh  + (size_t)B_ * 3072;  // B x 2048  [h_new | context]
    float* q   = cat + (size_t)B_ * 2048;  // B x 1024
    float* co  = q   + (size_t)B_ * 1024;  // B x 1024  (tanh concat output)

    // 1. build x
    hipLaunchKernelGGL(build_x_kernel, dim3(B_), dim3(256), 0, stream,
                       seq, c2n, c2f, emb, semb, nemb, x);

    // 2. gi = x @ W_ih.T + b_ih   [128,3072], K=1088
    hipLaunchKernelGGL((gemm128_kernel<true, false>), dim3(48), dim3(256), 0, stream,
                       x, INDIM, W_ih, INDIM, b_ih, gi, 3072, 3072, INDIM);
    // 3. gh = h @ W_hh.T + b_hh   [128,3072], K=1024
    hipLaunchKernelGGL((gemm128_kernel<true, false>), dim3(48), dim3(256), 0, stream,
                       lh, H_, W_hh, H_, b_hh, gh, 3072, 3072, H_);
    // 4. gates -> h_new (into cat[:, :1024] and d_out hidden)
    hipLaunchKernelGGL(gru_gates_kernel, dim3((B_ * H_) / 256), dim3(256), 0, stream,
                       gi, gh, lh, cat, hidden);
    // 5. q = h_new @ W_attn       [128,1024], K=1024 (NT)
    hipLaunchKernelGGL((gemm128_kernel<false, false>), dim3(16), dim3(256), 0, stream,
                       cat, 2048, W_attn, H_, (const float*)nullptr, q, H_, H_, H_);
    // 6. attention fused: energies/softmax/context
    hipLaunchKernelGGL(attn_kernel, dim3(B_), dim3(256), 0, stream,
                       q, enc, cat, attnw);
    // 7. co = tanh(cat @ W_cat.T + b_cat)  [128,1024], K=2048
    hipLaunchKernelGGL((gemm128_kernel<true, true>), dim3(16), dim3(256), 0, stream,
                       cat, 2048, W_cat, 2048, b_cat, co, H_, H_, 2048);
    // 8. out = co @ W_out.T + b_out  [128,50000], K=1024
    hipLaunchKernelGGL((gemm128_kernel<true, false>), dim3((V_ + 63) / 64), dim3(256), 0, stream,
                       co, H_, W_out, H_, b_out, out, V_, V_, H_);
}

// Round 2
// 386.072 us; speedup vs baseline: 2.6130x; 2.6130x over previous
//
#include <hip/hip_runtime.h>
#include <hip/hip_bf16.h>
#include <cstddef>

#define B_   128
#define L_   128
#define H_   1024
#define V_   50000
#define INDIM 1088   // H + 32 + 32

typedef short short8 __attribute__((ext_vector_type(8)));
typedef float f32x4  __attribute__((ext_vector_type(4)));
typedef unsigned short ushort8 __attribute__((ext_vector_type(8)));

// f32 -> bf16 bits, round-to-nearest-even
static __device__ __forceinline__ unsigned short f2bf(float f) {
    unsigned u = __builtin_bit_cast(unsigned, f);
    u = u + 0x7FFFu + ((u >> 16) & 1u);
    return (unsigned short)(u >> 16);
}
static __device__ __forceinline__ float bf2f(unsigned short h) {
    unsigned u = ((unsigned)h) << 16;
    return __builtin_bit_cast(float, u);
}

// ---------------------------------------------------------------------------
// build x = [emb[idx] | sound_emb | num_emb]
// ---------------------------------------------------------------------------
__global__ __launch_bounds__(256) void build_x_kernel(
    const int* __restrict__ seq, const int* __restrict__ c2n,
    const int* __restrict__ c2f, const float* __restrict__ emb,
    const float* __restrict__ semb, const float* __restrict__ nemb,
    float* __restrict__ x)
{
    const int b = blockIdx.x;
    const int t = threadIdx.x;
    const int idx = seq[b];
    float* xb = x + (size_t)b * INDIM;
    const float* eb = emb + (size_t)idx * H_;
    ((float4*)xb)[t] = ((const float4*)eb)[t];
    if (t < 32) {
        xb[1024 + t] = semb[c2f[idx] * 32 + t];
        xb[1056 + t] = nemb[c2n[idx] * 32 + t];
    }
}

// ---------------------------------------------------------------------------
// bf16 MFMA GEMM: C[128, N] = A[128, K] @ W^T (+bias)(+tanh)
//   WT=true : W is [N,K] row-major.  WT=false: W is [K,N] row-major.
//   SPLIT=true: split-f32 (hi+lo bf16, 3 MFMA passes) for ~2^-16 accuracy.
// Tile BM=128 x BN=64, BK=64. 256 threads = 4 waves (2x2), wave tile 64x32.
// LDS rows padded to 72 bf16 (144 B) -> conflict-floor ds_read_b128.
// ---------------------------------------------------------------------------
template<bool WT, bool SPLIT, bool TANH>
__global__ __launch_bounds__(256) void mfma_gemm(
    const float* __restrict__ A, int lda,
    const float* __restrict__ W, int ldw,
    const float* __restrict__ bias,
    float* __restrict__ C, int ldc,
    int N, int K)
{
    __shared__ unsigned short As_h[128][72];
    __shared__ unsigned short Ws_h[64][72];
    __shared__ unsigned short As_l[SPLIT ? 128 : 1][72];
    __shared__ unsigned short Ws_l[SPLIT ? 64 : 1][72];

    const int t    = threadIdx.x;
    const int lane = t & 63;
    const int wv   = t >> 6;
    const int wr   = wv >> 1;        // 0..1
    const int wc   = wv & 1;         // 0..1
    const int n0   = blockIdx.x * 64;
    const int l15  = lane & 15;
    const int g    = lane >> 4;      // 0..3 k-group

    f32x4 acc[4][2];
#pragma unroll
    for (int i = 0; i < 4; i++)
#pragma unroll
        for (int j = 0; j < 2; j++) acc[i][j] = (f32x4){0.f, 0.f, 0.f, 0.f};

    for (int k0 = 0; k0 < K; k0 += 64) {
        // ---- stage A[128][64] ----
        {
            const int row  = t >> 1;
            const int half = t & 1;
            const float* ar = A + (size_t)row * lda + k0 + half * 32;
#pragma unroll
            for (int i = 0; i < 4; i++) {
                float4 v0 = *(const float4*)&ar[i * 8];
                float4 v1 = *(const float4*)&ar[i * 8 + 4];
                float fv[8] = {v0.x, v0.y, v0.z, v0.w, v1.x, v1.y, v1.z, v1.w};
                ushort8 hh, ll;
#pragma unroll
                for (int e = 0; e < 8; e++) {
                    unsigned short hb = f2bf(fv[e]);
                    hh[e] = hb;
                    if constexpr (SPLIT) ll[e] = f2bf(fv[e] - bf2f(hb));
                }
                *(ushort8*)&As_h[row][half * 32 + i * 8] = hh;
                if constexpr (SPLIT) *(ushort8*)&As_l[row][half * 32 + i * 8] = ll;
            }
        }
        // ---- stage W -> Ws[64][64] (bf16, [n][k]) ----
        if constexpr (WT) {
            const int n  = t >> 2;
            const int q4 = t & 3;
            const int gn = n0 + n;
            const float* wr_ = W + (size_t)gn * ldw + k0 + q4 * 16;
#pragma unroll
            for (int i = 0; i < 2; i++) {
                float fv[8];
                if (gn < N) {
                    float4 v0 = *(const float4*)&wr_[i * 8];
                    float4 v1 = *(const float4*)&wr_[i * 8 + 4];
                    fv[0]=v0.x; fv[1]=v0.y; fv[2]=v0.z; fv[3]=v0.w;
                    fv[4]=v1.x; fv[5]=v1.y; fv[6]=v1.z; fv[7]=v1.w;
                } else {
#pragma unroll
                    for (int e = 0; e < 8; e++) fv[e] = 0.f;
                }
                ushort8 hh, ll;
#pragma unroll
                for (int e = 0; e < 8; e++) {
                    unsigned short hb = f2bf(fv[e]);
                    hh[e] = hb;
                    if constexpr (SPLIT) ll[e] = f2bf(fv[e] - bf2f(hb));
                }
                *(ushort8*)&Ws_h[n][q4 * 16 + i * 8] = hh;
                if constexpr (SPLIT) *(ushort8*)&Ws_l[n][q4 * 16 + i * 8] = ll;
            }
        } else {
            // W[K,N]: transpose-stage. thread reads 4 n at one k.
            const int kk = t >> 4;          // 0..15
            const int n4 = (t & 15) * 4;
#pragma unroll
            for (int i = 0; i < 4; i++) {
                const int k = kk + i * 16;
                float4 v = *(const float4*)&W[(size_t)(k0 + k) * ldw + n0 + n4];
                float fv[4] = {v.x, v.y, v.z, v.w};
#pragma unroll
                for (int j = 0; j < 4; j++) {
                    unsigned short hb = f2bf(fv[j]);
                    Ws_h[n4 + j][k] = hb;
                    if constexpr (SPLIT) Ws_l[n4 + j][k] = f2bf(fv[j] - bf2f(hb));
                }
            }
        }
        __syncthreads();

        // ---- MFMA: two K=32 sub-chunks ----
#pragma unroll
        for (int ks = 0; ks < 2; ks++) {
            const int ko = ks * 32 + g * 8;
            short8 ah[4], bh[2];
#pragma unroll
            for (int mi = 0; mi < 4; mi++)
                ah[mi] = *(const short8*)&As_h[wr * 64 + mi * 16 + l15][ko];
#pragma unroll
            for (int ni = 0; ni < 2; ni++)
                bh[ni] = *(const short8*)&Ws_h[wc * 32 + ni * 16 + l15][ko];
            if constexpr (SPLIT) {
                short8 al[4], bl[2];
#pragma unroll
                for (int mi = 0; mi < 4; mi++)
                    al[mi] = *(const short8*)&As_l[wr * 64 + mi * 16 + l15][ko];
#pragma unroll
                for (int ni = 0; ni < 2; ni++)
                    bl[ni] = *(const short8*)&Ws_l[wc * 32 + ni * 16 + l15][ko];
#pragma unroll
                for (int mi = 0; mi < 4; mi++)
#pragma unroll
                    for (int ni = 0; ni < 2; ni++) {
                        acc[mi][ni] = __builtin_amdgcn_mfma_f32_16x16x32_bf16(ah[mi], bh[ni], acc[mi][ni], 0, 0, 0);
                        acc[mi][ni] = __builtin_amdgcn_mfma_f32_16x16x32_bf16(ah[mi], bl[ni], acc[mi][ni], 0, 0, 0);
                        acc[mi][ni] = __builtin_amdgcn_mfma_f32_16x16x32_bf16(al[mi], bh[ni], acc[mi][ni], 0, 0, 0);
                    }
            } else {
#pragma unroll
                for (int mi = 0; mi < 4; mi++)
#pragma unroll
                    for (int ni = 0; ni < 2; ni++)
                        acc[mi][ni] = __builtin_amdgcn_mfma_f32_16x16x32_bf16(ah[mi], bh[ni], acc[mi][ni], 0, 0, 0);
            }
        }
        __syncthreads();
    }

    // ---- epilogue: C row = m, col = n; D layout col=lane&15, row=(lane>>4)*4+r
#pragma unroll
    for (int mi = 0; mi < 4; mi++) {
#pragma unroll
        for (int ni = 0; ni < 2; ni++) {
            const int col = n0 + wc * 32 + ni * 16 + l15;
            if (col < N) {
                const float bb = bias ? bias[col] : 0.f;
#pragma unroll
                for (int r = 0; r < 4; r++) {
                    const int row = wr * 64 + mi * 16 + g * 4 + r;
                    float v = acc[mi][ni][r] + bb;
                    if (TANH) v = tanhf(v);
                    C[(size_t)row * ldc + col] = v;
                }
            }
        }
    }
}

// ---------------------------------------------------------------------------
// GRU gates (r,z,n). h_new -> cat[:, :1024] and d_out hidden.
// ---------------------------------------------------------------------------
__global__ __launch_bounds__(256) void gru_gates_kernel(
    const float* __restrict__ gi, const float* __restrict__ gh,
    const float* __restrict__ h_prev,
    float* __restrict__ cat, float* __restrict__ hid_out)
{
    const int id = blockIdx.x * 256 + threadIdx.x;
    const int b = id >> 10;
    const int j = id & 1023;
    const float ir = gi[(size_t)b * 3072 + j];
    const float iz = gi[(size_t)b * 3072 + 1024 + j];
    const float in_ = gi[(size_t)b * 3072 + 2048 + j];
    const float hr = gh[(size_t)b * 3072 + j];
    const float hz = gh[(size_t)b * 3072 + 1024 + j];
    const float hn = gh[(size_t)b * 3072 + 2048 + j];
    const float r = 1.f / (1.f + __expf(-(ir + hr)));
    const float z = 1.f / (1.f + __expf(-(iz + hz)));
    const float n = tanhf(in_ + r * hn);
    const float h = (1.f - z) * n + z * h_prev[id];
    cat[(size_t)b * 2048 + j] = h;
    hid_out[id] = h;
}

// ---------------------------------------------------------------------------
// Attention pass 1: partial energies. grid (4 slices, 128 b), 256 thr.
// epart[(b*128+l)*4 + s] = q[b, s*256:+256] . enc[l, b, s*256:+256]
// ---------------------------------------------------------------------------
__global__ __launch_bounds__(256) void energy_partial_kernel(
    const float* __restrict__ q, const float* __restrict__ enc,
    float* __restrict__ epart)
{
    const int s = blockIdx.x, b = blockIdx.y;
    const int t = threadIdx.x, lane = t & 63, wv = t >> 6;
    __shared__ float q_s[256];
    q_s[t] = q[(size_t)b * H_ + s * 256 + t];
    __syncthreads();
    const float4 qv = *(const float4*)&q_s[lane * 4];
    const float* encb = enc + (size_t)b * H_ + s * 256;
    for (int l0 = 0; l0 < 32; l0++) {
        const int l = wv * 32 + l0;
        float4 ev = *(const float4*)&encb[(size_t)l * (B_ * H_) + lane * 4];
        float p = ev.x * qv.x + ev.y * qv.y + ev.z * qv.z + ev.w * qv.w;
#pragma unroll
        for (int off = 32; off > 0; off >>= 1) p += __shfl_xor(p, off);
        if (lane == 0) epart[((size_t)b * 128 + l) * 4 + s] = p;
    }
}

// ---------------------------------------------------------------------------
// Attention pass 2: softmax over L=128. grid 128 b, 128 thr (2 waves).
// ---------------------------------------------------------------------------
__global__ __launch_bounds__(128) void attn_softmax_kernel(
    const float* __restrict__ epart, float* __restrict__ attnw)
{
    const int b = blockIdx.x, t = threadIdx.x;
    const int lane = t & 63, wv = t >> 6;
    __shared__ float red[2];
    float4 pe = *(const float4*)&epart[((size_t)b * 128 + t) * 4];
    const float e = pe.x + pe.y + pe.z + pe.w;
    float mx = e;
#pragma unroll
    for (int off = 32; off > 0; off >>= 1) mx = fmaxf(mx, __shfl_xor(mx, off));
    if (lane == 0) red[wv] = mx;
    __syncthreads();
    const float gm = fmaxf(red[0], red[1]);
    __syncthreads();
    const float ex = __expf(e - gm);
    float sm = ex;
#pragma unroll
    for (int off = 32; off > 0; off >>= 1) sm += __shfl_xor(sm, off);
    if (lane == 0) red[wv] = sm;
    __syncthreads();
    attnw[(size_t)b * L_ + t] = ex / (red[0] + red[1]);
}

// ---------------------------------------------------------------------------
// Attention pass 3: context. grid (4 slices, 128 b), 256 thr.
// ---------------------------------------------------------------------------
__global__ __launch_bounds__(256) void context_kernel(
    const float* __restrict__ attnw, const float* __restrict__ enc,
    float* __restrict__ cat)
{
    const int s = blockIdx.x, b = blockIdx.y, t = threadIdx.x;
    __shared__ float w_s[128];
    if (t < 128) w_s[t] = attnw[(size_t)b * L_ + t];
    __syncthreads();
    const int h = s * 256 + t;
    const float* encb = enc + (size_t)b * H_ + h;
    float c = 0.f;
#pragma unroll 4
    for (int l = 0; l < 128; l++)
        c += w_s[l] * encb[(size_t)l * (B_ * H_)];
    cat[(size_t)b * 2048 + 1024 + h] = c;
}

// ---------------------------------------------------------------------------
extern "C" void kernel_launch(void* const* d_in, const int* in_sizes, int n_in,
                              void* d_out, int out_size, void* d_ws, size_t ws_size,
                              hipStream_t stream)
{
    const int*   seq    = (const int*)  d_in[0];
    const float* lh     = (const float*)d_in[1];
    const float* enc    = (const float*)d_in[2];
    const int*   c2n    = (const int*)  d_in[3];
    const int*   c2f    = (const int*)  d_in[4];
    const float* emb    = (const float*)d_in[5];
    const float* semb   = (const float*)d_in[6];
    const float* nemb   = (const float*)d_in[7];
    const float* W_ih   = (const float*)d_in[8];
    const float* W_hh   = (const float*)d_in[9];
    const float* b_ih   = (const float*)d_in[10];
    const float* b_hh   = (const float*)d_in[11];
    const float* W_attn = (const float*)d_in[12];
    // d_in[13] = b_attn: dropped (softmax shift-invariant, exact)
    const float* W_cat  = (const float*)d_in[14];
    const float* b_cat  = (const float*)d_in[15];
    const float* W_out  = (const float*)d_in[16];
    const float* b_out  = (const float*)d_in[17];

    float* out    = (float*)d_out;
    float* hidden = out + (size_t)B_ * V_;
    float* attnw  = hidden + (size_t)B_ * H_;

    float* ws  = (float*)d_ws;
    float* x     = ws;                       // B x 1088 (dead after gi)
    float* epart = ws;                       // B x 128 x 4 (aliases x, used later)
    float* gi  = x   + (size_t)B_ * INDIM;   // B x 3072
    float* gh  = gi  + (size_t)B_ * 3072;    // B x 3072
    float* cat = gh  + (size_t)B_ * 3072;    // B x 2048
    float* q   = cat + (size_t)B_ * 2048;    // B x 1024
    float* co  = q   + (size_t)B_ * 1024;    // B x 1024

    // 1. build x
    hipLaunchKernelGGL(build_x_kernel, dim3(B_), dim3(256), 0, stream,
                       seq, c2n, c2f, emb, semb, nemb, x);
    // 2. gi = x @ W_ih.T + b_ih  (split bf16: feeds attnw-critical chain)
    hipLaunchKernelGGL((mfma_gemm<true, true, false>), dim3(48), dim3(256), 0, stream,
                       x, INDIM, W_ih, INDIM, b_ih, gi, 3072, 3072, INDIM);
    // 3. gh = h @ W_hh.T + b_hh  (split)
    hipLaunchKernelGGL((mfma_gemm<true, true, false>), dim3(48), dim3(256), 0, stream,
                       lh, H_, W_hh, H_, b_hh, gh, 3072, 3072, H_);
    // 4. gates
    hipLaunchKernelGGL(gru_gates_kernel, dim3((B_ * H_) / 256), dim3(256), 0, stream,
                       gi, gh, lh, cat, hidden);
    // 5. q = h_new @ W_attn  (NT, split)
    hipLaunchKernelGGL((mfma_gemm<false, true, false>), dim3(16), dim3(256), 0, stream,
                       cat, 2048, W_attn, H_, (const float*)nullptr, q, H_, H_, H_);
    // 6-8. attention: energies -> softmax -> context
    hipLaunchKernelGGL(energy_partial_kernel, dim3(4, 128), dim3(256), 0, stream,
                       q, enc, epart);
    hipLaunchKernelGGL(attn_softmax_kernel, dim3(128), dim3(128), 0, stream,
                       epart, attnw);
    hipLaunchKernelGGL(context_kernel, dim3(4, 128), dim3(256), 0, stream,
                       attnw, enc, cat);
    // 9. co = tanh(cat @ W_cat.T + b_cat)  (single-pass bf16)
    hipLaunchKernelGGL((mfma_gemm<true, false, true>), dim3(16), dim3(256), 0, stream,
                       cat, 2048, W_cat, 2048, b_cat, co, H_, H_, 2048);
    // 10. out = co @ W_out.T + b_out
    hipLaunchKernelGGL((mfma_gemm<true, false, false>), dim3((V_ + 63) / 64), dim3(256), 0, stream,
                       co, H_, W_out, H_, b_out, out, V_, V_, H_);
}

// Round 3
// 175.167 us; speedup vs baseline: 5.7592x; 2.2040x over previous
//
#include <hip/hip_runtime.h>
#include <hip/hip_bf16.h>
#include <cstddef>

#define B_   128
#define L_   128
#define H_   1024
#define V_   50000
#define INDIM 1088   // H + 32 + 32

typedef short short8 __attribute__((ext_vector_type(8)));
typedef unsigned short ushort8 __attribute__((ext_vector_type(8)));
typedef unsigned short ushort4v __attribute__((ext_vector_type(4)));
typedef float f32x4 __attribute__((ext_vector_type(4)));

static __device__ __forceinline__ unsigned short f2bf(float f) {
    unsigned u = __builtin_bit_cast(unsigned, f);
    u = u + 0x7FFFu + ((u >> 16) & 1u);
    return (unsigned short)(u >> 16);
}
static __device__ __forceinline__ float bf2f(unsigned short h) {
    unsigned u = ((unsigned)h) << 16;
    return __builtin_bit_cast(float, u);
}
static __device__ __forceinline__ float sigm(float v) {
    return 1.f / (1.f + __expf(-v));
}

// ---------------------------------------------------------------------------
// prep: x = [emb|semb|nemb] and h = lh, both as bf16 hi/lo planes
// ---------------------------------------------------------------------------
__global__ __launch_bounds__(256) void prep_kernel(
    const int* __restrict__ seq, const int* __restrict__ c2n,
    const int* __restrict__ c2f, const float* __restrict__ emb,
    const float* __restrict__ semb, const float* __restrict__ nemb,
    const float* __restrict__ lh,
    unsigned short* __restrict__ x_hi, unsigned short* __restrict__ x_lo,
    unsigned short* __restrict__ h_hi, unsigned short* __restrict__ h_lo)
{
    const int b = blockIdx.x, t = threadIdx.x;
    const int idx = seq[b];
    for (int i = t; i < 528; i += 256) {
        float4 v;
        unsigned short *dh, *dl;
        int off;
        if (i < 272) {
            if (i < 256) {
                v = *(const float4*)&emb[(size_t)idx * H_ + i * 4];
            } else {
                const int j = i - 256;
                if (j < 8) v = *(const float4*)&semb[c2f[idx] * 32 + j * 4];
                else       v = *(const float4*)&nemb[c2n[idx] * 32 + (j - 8) * 4];
            }
            dh = x_hi + (size_t)b * INDIM; dl = x_lo + (size_t)b * INDIM; off = i * 4;
        } else {
            const int j = i - 272;
            v = *(const float4*)&lh[(size_t)b * H_ + j * 4];
            dh = h_hi + (size_t)b * H_; dl = h_lo + (size_t)b * H_; off = j * 4;
        }
        const float fv[4] = {v.x, v.y, v.z, v.w};
        ushort4v hh, ll;
#pragma unroll
        for (int e = 0; e < 4; e++) {
            hh[e] = f2bf(fv[e]);
            ll[e] = f2bf(fv[e] - bf2f(hh[e]));
        }
        *(ushort4v*)&dh[off] = hh;
        *(ushort4v*)&dl[off] = ll;
    }
}

// ---------------------------------------------------------------------------
// Streaming MFMA GEMM: C[128, N] (+slice partials) = A(bf16 hi/lo) @ W(f32)^T
//   WT: W [N,K] row-major; !WT: W [K,N] row-major.
//   SPLIT: 3-MFMA hi/lo product for ~f32 accuracy.
// BM=128, BN=64, BK=64; 256 thr = 4 waves (2x2), wave tile 64x32.
// Register prefetch: loads for k+1 issued before staging/MFMA of k.
// Split-K via blockIdx.y: slice0 len k_len0, others k_lenB; partial out at
// C + y*pstride (bias/tanh only meaningful when grid.y==1).
// ---------------------------------------------------------------------------
template<bool WT, bool SPLIT, bool TANH>
__global__ __launch_bounds__(256, SPLIT ? 2 : 4) void sgemm(
    const unsigned short* __restrict__ Ah, const unsigned short* __restrict__ Al, int lda,
    const float* __restrict__ W, int ldw,
    const float* __restrict__ bias,
    float* __restrict__ C, int ldc, size_t pstride,
    int N, int k_len0, int k_lenB)
{
    __shared__ unsigned short As_h[128][72];
    __shared__ unsigned short Ws_h[64][72];
    __shared__ unsigned short As_l[SPLIT ? 128 : 1][72];
    __shared__ unsigned short Ws_l[SPLIT ? 64 : 1][72];

    const int t    = threadIdx.x;
    const int lane = t & 63;
    const int wv   = t >> 6;
    const int wr   = wv >> 1;
    const int wc   = wv & 1;
    const int n0   = blockIdx.x * 64;
    const int l15  = lane & 15;
    const int g    = lane >> 4;

    const int y     = blockIdx.y;
    const int k_off = (y == 0) ? 0 : k_len0 + (y - 1) * k_lenB;
    const int k_len = (y == 0) ? k_len0 : k_lenB;
    float* Cp = C + (size_t)y * pstride;

    // A staging map: round i -> row (t>>3)+i*32, col chunk (t&7)*8 shorts
    const int ar = t >> 3;
    const int ac = (t & 7) * 8;
    // W(WT) map: row n=t>>2, float4 j at [n][j*16 + (t&3)*4]
    const int wn = t >> 2, wq = t & 3;
    // W(NT) map: k = (t>>4)+j*16, 4 n at (t&15)*4
    const int nk = t >> 4, nn4 = (t & 15) * 4;

    f32x4 acc[4][2];
#pragma unroll
    for (int i = 0; i < 4; i++)
#pragma unroll
        for (int j = 0; j < 2; j++) acc[i][j] = (f32x4){0.f, 0.f, 0.f, 0.f};

#define LOAD_REGS(K0, RA, RAL, RW) do {                                        \
    _Pragma("unroll")                                                          \
    for (int i_ = 0; i_ < 4; i_++)                                             \
        RA[i_] = *(const ushort8*)&Ah[(size_t)(ar + i_ * 32) * lda + (K0) + ac]; \
    if constexpr (SPLIT) {                                                     \
        _Pragma("unroll")                                                      \
        for (int i_ = 0; i_ < 4; i_++)                                         \
            RAL[i_] = *(const ushort8*)&Al[(size_t)(ar + i_ * 32) * lda + (K0) + ac]; \
    }                                                                          \
    if constexpr (WT) {                                                        \
        const bool ok_ = (n0 + wn) < N;                                        \
        const float* wb_ = W + (size_t)(n0 + wn) * ldw + (K0);                 \
        _Pragma("unroll")                                                      \
        for (int j_ = 0; j_ < 4; j_++)                                         \
            RW[j_] = ok_ ? *(const float4*)&wb_[j_ * 16 + wq * 4]              \
                         : make_float4(0.f, 0.f, 0.f, 0.f);                    \
    } else {                                                                   \
        _Pragma("unroll")                                                      \
        for (int j_ = 0; j_ < 4; j_++)                                         \
            RW[j_] = *(const float4*)&W[(size_t)((K0) + nk + j_ * 16) * ldw + n0 + nn4]; \
    }                                                                          \
} while (0)

#define STAGE_REGS(RA, RAL, RW) do {                                           \
    _Pragma("unroll")                                                          \
    for (int i_ = 0; i_ < 4; i_++) {                                           \
        *(ushort8*)&As_h[ar + i_ * 32][ac] = RA[i_];                           \
        if constexpr (SPLIT) *(ushort8*)&As_l[ar + i_ * 32][ac] = RAL[i_];     \
    }                                                                          \
    if constexpr (WT) {                                                        \
        _Pragma("unroll")                                                      \
        for (int j_ = 0; j_ < 4; j_++) {                                       \
            const float fv_[4] = {RW[j_].x, RW[j_].y, RW[j_].z, RW[j_].w};     \
            ushort4v hh_, ll_;                                                 \
            _Pragma("unroll")                                                  \
            for (int e_ = 0; e_ < 4; e_++) {                                   \
                hh_[e_] = f2bf(fv_[e_]);                                       \
                if constexpr (SPLIT) ll_[e_] = f2bf(fv_[e_] - bf2f(hh_[e_]));  \
            }                                                                  \
            *(ushort4v*)&Ws_h[wn][j_ * 16 + wq * 4] = hh_;                     \
            if constexpr (SPLIT) *(ushort4v*)&Ws_l[wn][j_ * 16 + wq * 4] = ll_; \
        }                                                                      \
    } else {                                                                   \
        _Pragma("unroll")                                                      \
        for (int j_ = 0; j_ < 4; j_++) {                                       \
            const float fv_[4] = {RW[j_].x, RW[j_].y, RW[j_].z, RW[j_].w};     \
            _Pragma("unroll")                                                  \
            for (int e_ = 0; e_ < 4; e_++) {                                   \
                const unsigned short hb_ = f2bf(fv_[e_]);                      \
                Ws_h[nn4 + e_][nk + j_ * 16] = hb_;                            \
                if constexpr (SPLIT)                                           \
                    Ws_l[nn4 + e_][nk + j_ * 16] = f2bf(fv_[e_] - bf2f(hb_));  \
            }                                                                  \
        }                                                                      \
    }                                                                          \
} while (0)

    ushort8 ra[4], ral[4];
    float4 rw[4];
    LOAD_REGS(k_off, ra, ral, rw);

    const int k_end = k_off + k_len;
    for (int k0 = k_off; k0 < k_end; k0 += 64) {
        ushort8 nb[4], nbl[4];
        float4 nw[4];
        const bool more = (k0 + 64) < k_end;
        if (more) LOAD_REGS(k0 + 64, nb, nbl, nw);

        STAGE_REGS(ra, ral, rw);
        __syncthreads();

#pragma unroll
        for (int ks = 0; ks < 2; ks++) {
            const int ko = ks * 32 + g * 8;
            short8 ah[4], bh[2];
#pragma unroll
            for (int mi = 0; mi < 4; mi++)
                ah[mi] = *(const short8*)&As_h[wr * 64 + mi * 16 + l15][ko];
#pragma unroll
            for (int ni = 0; ni < 2; ni++)
                bh[ni] = *(const short8*)&Ws_h[wc * 32 + ni * 16 + l15][ko];
            if constexpr (SPLIT) {
                short8 al[4], bl[2];
#pragma unroll
                for (int mi = 0; mi < 4; mi++)
                    al[mi] = *(const short8*)&As_l[wr * 64 + mi * 16 + l15][ko];
#pragma unroll
                for (int ni = 0; ni < 2; ni++)
                    bl[ni] = *(const short8*)&Ws_l[wc * 32 + ni * 16 + l15][ko];
#pragma unroll
                for (int mi = 0; mi < 4; mi++)
#pragma unroll
                    for (int ni = 0; ni < 2; ni++) {
                        acc[mi][ni] = __builtin_amdgcn_mfma_f32_16x16x32_bf16(ah[mi], bh[ni], acc[mi][ni], 0, 0, 0);
                        acc[mi][ni] = __builtin_amdgcn_mfma_f32_16x16x32_bf16(ah[mi], bl[ni], acc[mi][ni], 0, 0, 0);
                        acc[mi][ni] = __builtin_amdgcn_mfma_f32_16x16x32_bf16(al[mi], bh[ni], acc[mi][ni], 0, 0, 0);
                    }
            } else {
#pragma unroll
                for (int mi = 0; mi < 4; mi++)
#pragma unroll
                    for (int ni = 0; ni < 2; ni++)
                        acc[mi][ni] = __builtin_amdgcn_mfma_f32_16x16x32_bf16(ah[mi], bh[ni], acc[mi][ni], 0, 0, 0);
            }
        }
        __syncthreads();

        if (more) {
#pragma unroll
            for (int i = 0; i < 4; i++) {
                ra[i] = nb[i];
                if constexpr (SPLIT) ral[i] = nbl[i];
            }
#pragma unroll
            for (int j = 0; j < 4; j++) rw[j] = nw[j];
        }
    }
#undef LOAD_REGS
#undef STAGE_REGS

#pragma unroll
    for (int mi = 0; mi < 4; mi++) {
#pragma unroll
        for (int ni = 0; ni < 2; ni++) {
            const int col = n0 + wc * 32 + ni * 16 + l15;
            if (col < N) {
                const float bb = bias ? bias[col] : 0.f;
#pragma unroll
                for (int r = 0; r < 4; r++) {
                    const int row = wr * 64 + mi * 16 + g * 4 + r;
                    float v = acc[mi][ni][r] + bb;
                    if (TANH) v = tanhf(v);
                    Cp[(size_t)row * ldc + col] = v;
                }
            }
        }
    }
}

// ---------------------------------------------------------------------------
// GRU gates: sums 4 k-slice partials of gi/gh, adds biases, computes h.
// Writes hidden (f32, d_out) and cat hi/lo planes (h half).
// ---------------------------------------------------------------------------
__global__ __launch_bounds__(256) void gru_gates_kernel(
    const float* __restrict__ gi, const float* __restrict__ gh,
    const float* __restrict__ b_ih, const float* __restrict__ b_hh,
    const float* __restrict__ h_prev,
    float* __restrict__ hid_out,
    unsigned short* __restrict__ cat_hi, unsigned short* __restrict__ cat_lo)
{
    const int id = blockIdx.x * 256 + threadIdx.x;
    const int b = id >> 10, j = id & 1023;
    const size_t base = (size_t)b * 3072 + j;
    float ir = b_ih[j], iz = b_ih[1024 + j], in_ = b_ih[2048 + j];
    float hr = b_hh[j], hz = b_hh[1024 + j], hn = b_hh[2048 + j];
#pragma unroll
    for (int p = 0; p < 4; p++) {
        const float* gp = gi + (size_t)p * (128 * 3072);
        const float* hp = gh + (size_t)p * (128 * 3072);
        ir += gp[base]; iz += gp[base + 1024]; in_ += gp[base + 2048];
        hr += hp[base]; hz += hp[base + 1024]; hn += hp[base + 2048];
    }
    const float r = sigm(ir + hr);
    const float z = sigm(iz + hz);
    const float n = tanhf(in_ + r * hn);
    const float h = (1.f - z) * n + z * h_prev[id];
    hid_out[id] = h;
    const unsigned short hb = f2bf(h);
    cat_hi[(size_t)b * 2048 + j] = hb;
    cat_lo[(size_t)b * 2048 + j] = f2bf(h - bf2f(hb));
}

// ---------------------------------------------------------------------------
// energies (partial over 4 h-slices), summing 4 q k-slice partials on load
// ---------------------------------------------------------------------------
__global__ __launch_bounds__(256) void energy_partial_kernel(
    const float* __restrict__ qp, const float* __restrict__ enc,
    float* __restrict__ epart)
{
    const int s = blockIdx.x, b = blockIdx.y;
    const int t = threadIdx.x, lane = t & 63, wv = t >> 6;
    __shared__ float q_s[256];
    {
        const size_t o = (size_t)b * H_ + s * 256 + t;
        q_s[t] = qp[o] + qp[o + 131072] + qp[o + 262144] + qp[o + 393216];
    }
    __syncthreads();
    const float4 qv = *(const float4*)&q_s[lane * 4];
    const float* encb = enc + (size_t)b * H_ + s * 256;
    for (int l0 = 0; l0 < 32; l0++) {
        const int l = wv * 32 + l0;
        float4 ev = *(const float4*)&encb[(size_t)l * (B_ * H_) + lane * 4];
        float p = ev.x * qv.x + ev.y * qv.y + ev.z * qv.z + ev.w * qv.w;
#pragma unroll
        for (int off = 32; off > 0; off >>= 1) p += __shfl_xor(p, off);
        if (lane == 0) epart[((size_t)b * 128 + l) * 4 + s] = p;
    }
}

__global__ __launch_bounds__(128) void attn_softmax_kernel(
    const float* __restrict__ epart, float* __restrict__ attnw)
{
    const int b = blockIdx.x, t = threadIdx.x;
    const int lane = t & 63, wv = t >> 6;
    __shared__ float red[2];
    float4 pe = *(const float4*)&epart[((size_t)b * 128 + t) * 4];
    const float e = pe.x + pe.y + pe.z + pe.w;
    float mx = e;
#pragma unroll
    for (int off = 32; off > 0; off >>= 1) mx = fmaxf(mx, __shfl_xor(mx, off));
    if (lane == 0) red[wv] = mx;
    __syncthreads();
    const float gm = fmaxf(red[0], red[1]);
    __syncthreads();
    const float ex = __expf(e - gm);
    float sm = ex;
#pragma unroll
    for (int off = 32; off > 0; off >>= 1) sm += __shfl_xor(sm, off);
    if (lane == 0) red[wv] = sm;
    __syncthreads();
    attnw[(size_t)b * L_ + t] = ex / (red[0] + red[1]);
}

// context -> cat_hi ctx half (bf16)
__global__ __launch_bounds__(256) void context_kernel(
    const float* __restrict__ attnw, const float* __restrict__ enc,
    unsigned short* __restrict__ cat_hi)
{
    const int s = blockIdx.x, b = blockIdx.y, t = threadIdx.x;
    __shared__ float w_s[128];
    if (t < 128) w_s[t] = attnw[(size_t)b * L_ + t];
    __syncthreads();
    const int h = s * 256 + t;
    const float* encb = enc + (size_t)b * H_ + h;
    float c = 0.f;
#pragma unroll 4
    for (int l = 0; l < 128; l++)
        c += w_s[l] * encb[(size_t)l * (B_ * H_)];
    cat_hi[(size_t)b * 2048 + 1024 + h] = f2bf(c);
}

// co = tanh(sum of 4 partials + b_cat) -> bf16
__global__ __launch_bounds__(256) void co_reduce_kernel(
    const float* __restrict__ co_part, const float* __restrict__ b_cat,
    unsigned short* __restrict__ co_hi)
{
    const int id = blockIdx.x * 256 + threadIdx.x;
    const int j = id & 1023;
    float s = b_cat[j];
#pragma unroll
    for (int p = 0; p < 4; p++) s += co_part[(size_t)p * 131072 + id];
    co_hi[id] = f2bf(tanhf(s));
}

// ---------------------------------------------------------------------------
extern "C" void kernel_launch(void* const* d_in, const int* in_sizes, int n_in,
                              void* d_out, int out_size, void* d_ws, size_t ws_size,
                              hipStream_t stream)
{
    const int*   seq    = (const int*)  d_in[0];
    const float* lh     = (const float*)d_in[1];
    const float* enc    = (const float*)d_in[2];
    const int*   c2n    = (const int*)  d_in[3];
    const int*   c2f    = (const int*)  d_in[4];
    const float* emb    = (const float*)d_in[5];
    const float* semb   = (const float*)d_in[6];
    const float* nemb   = (const float*)d_in[7];
    const float* W_ih   = (const float*)d_in[8];
    const float* W_hh   = (const float*)d_in[9];
    const float* b_ih   = (const float*)d_in[10];
    const float* b_hh   = (const float*)d_in[11];
    const float* W_attn = (const float*)d_in[12];
    // d_in[13] = b_attn: dropped (softmax shift-invariant, exact)
    const float* W_cat  = (const float*)d_in[14];
    const float* b_cat  = (const float*)d_in[15];
    const float* W_out  = (const float*)d_in[16];
    const float* b_out  = (const float*)d_in[17];

    float* out    = (float*)d_out;
    float* hidden = out + (size_t)B_ * V_;
    float* attnw  = hidden + (size_t)B_ * H_;

    // ---- workspace layout ----
    unsigned short* x_hi   = (unsigned short*)d_ws;            // 128*1088
    unsigned short* x_lo   = x_hi   + (size_t)128 * INDIM;
    unsigned short* h_hi   = x_lo   + (size_t)128 * INDIM;     // 128*1024
    unsigned short* h_lo   = h_hi   + (size_t)128 * 1024;
    unsigned short* cat_hi = h_lo   + (size_t)128 * 1024;      // 128*2048
    unsigned short* cat_lo = cat_hi + (size_t)128 * 2048;
    unsigned short* co_hi  = cat_lo + (size_t)128 * 2048;      // 128*1024
    float* fbase   = (float*)(co_hi + (size_t)128 * 1024);
    float* gi_part = fbase;                                    // 4*128*3072
    float* gh_part = gi_part + (size_t)4 * 128 * 3072;         // 4*128*3072
    // aliases (gi/gh dead after gates):
    float* q_part  = fbase;                                    // 4*128*1024
    float* co_part = q_part + (size_t)4 * 128 * 1024;          // 4*128*1024
    float* epart   = co_part + (size_t)4 * 128 * 1024;         // 128*128*4

    // 1. prep: x, h bf16 hi/lo planes
    hipLaunchKernelGGL(prep_kernel, dim3(B_), dim3(256), 0, stream,
                       seq, c2n, c2f, emb, semb, nemb, lh, x_hi, x_lo, h_hi, h_lo);
    // 2. gi partials: K=1088 -> slices {320,256,256,256}
    hipLaunchKernelGGL((sgemm<true, true, false>), dim3(48, 4), dim3(256), 0, stream,
                       x_hi, x_lo, INDIM, W_ih, INDIM, (const float*)nullptr,
                       gi_part, 3072, (size_t)128 * 3072, 3072, 320, 256);
    // 3. gh partials: K=1024 -> 4 x 256
    hipLaunchKernelGGL((sgemm<true, true, false>), dim3(48, 4), dim3(256), 0, stream,
                       h_hi, h_lo, H_, W_hh, H_, (const float*)nullptr,
                       gh_part, 3072, (size_t)128 * 3072, 3072, 256, 256);
    // 4. gates -> hidden + cat planes
    hipLaunchKernelGGL(gru_gates_kernel, dim3(512), dim3(256), 0, stream,
                       gi_part, gh_part, b_ih, b_hh, lh, hidden, cat_hi, cat_lo);
    // 5. q partials = h @ W_attn (NT): K=1024 -> 4 x 256
    hipLaunchKernelGGL((sgemm<false, true, false>), dim3(16, 4), dim3(256), 0, stream,
                       cat_hi, cat_lo, 2048, W_attn, H_, (const float*)nullptr,
                       q_part, H_, (size_t)128 * 1024, H_, 256, 256);
    // 6-8. attention
    hipLaunchKernelGGL(energy_partial_kernel, dim3(4, 128), dim3(256), 0, stream,
                       q_part, enc, epart);
    hipLaunchKernelGGL(attn_softmax_kernel, dim3(128), dim3(128), 0, stream,
                       epart, attnw);
    hipLaunchKernelGGL(context_kernel, dim3(4, 128), dim3(256), 0, stream,
                       attnw, enc, cat_hi);
    // 9. co partials = cat @ W_cat.T: K=2048 -> 4 x 512
    hipLaunchKernelGGL((sgemm<true, false, false>), dim3(16, 4), dim3(256), 0, stream,
                       cat_hi, cat_hi, 2048, W_cat, 2048, (const float*)nullptr,
                       co_part, H_, (size_t)128 * 1024, H_, 512, 512);
    // 10. co = tanh(sum + b_cat) -> bf16
    hipLaunchKernelGGL(co_reduce_kernel, dim3(512), dim3(256), 0, stream,
                       co_part, b_cat, co_hi);
    // 11. out = co @ W_out.T + b_out
    hipLaunchKernelGGL((sgemm<true, false, false>), dim3((V_ + 63) / 64, 1), dim3(256), 0, stream,
                       co_hi, co_hi, H_, W_out, H_, b_out,
                       out, V_, (size_t)0, V_, H_, H_);
}

// Round 4
// 160.301 us; speedup vs baseline: 6.2932x; 1.0927x over previous
//
#include <hip/hip_runtime.h>
#include <hip/hip_bf16.h>
#include <cstddef>

#define B_   128
#define L_   128
#define H_   1024
#define V_   50000
#define INDIM 1088   // H + 32 + 32

typedef short short8 __attribute__((ext_vector_type(8)));
typedef unsigned short ushort8 __attribute__((ext_vector_type(8)));
typedef unsigned short ushort4v __attribute__((ext_vector_type(4)));
typedef float f32x4 __attribute__((ext_vector_type(4)));

static __device__ __forceinline__ unsigned short f2bf(float f) {
    unsigned u = __builtin_bit_cast(unsigned, f);
    u = u + 0x7FFFu + ((u >> 16) & 1u);
    return (unsigned short)(u >> 16);
}
static __device__ __forceinline__ float bf2f(unsigned short h) {
    unsigned u = ((unsigned)h) << 16;
    return __builtin_bit_cast(float, u);
}
static __device__ __forceinline__ float sigm(float v) {
    return 1.f / (1.f + __expf(-v));
}

// ---------------------------------------------------------------------------
// prep: x = [emb|semb|nemb] and h = lh, both as bf16 hi/lo planes
// ---------------------------------------------------------------------------
__global__ __launch_bounds__(256) void prep_kernel(
    const int* __restrict__ seq, const int* __restrict__ c2n,
    const int* __restrict__ c2f, const float* __restrict__ emb,
    const float* __restrict__ semb, const float* __restrict__ nemb,
    const float* __restrict__ lh,
    unsigned short* __restrict__ x_hi, unsigned short* __restrict__ x_lo,
    unsigned short* __restrict__ h_hi, unsigned short* __restrict__ h_lo)
{
    const int b = blockIdx.x, t = threadIdx.x;
    const int idx = seq[b];
    for (int i = t; i < 528; i += 256) {
        float4 v;
        unsigned short *dh, *dl;
        int off;
        if (i < 272) {
            if (i < 256) {
                v = *(const float4*)&emb[(size_t)idx * H_ + i * 4];
            } else {
                const int j = i - 256;
                if (j < 8) v = *(const float4*)&semb[c2f[idx] * 32 + j * 4];
                else       v = *(const float4*)&nemb[c2n[idx] * 32 + (j - 8) * 4];
            }
            dh = x_hi + (size_t)b * INDIM; dl = x_lo + (size_t)b * INDIM; off = i * 4;
        } else {
            const int j = i - 272;
            v = *(const float4*)&lh[(size_t)b * H_ + j * 4];
            dh = h_hi + (size_t)b * H_; dl = h_lo + (size_t)b * H_; off = j * 4;
        }
        const float fv[4] = {v.x, v.y, v.z, v.w};
        ushort4v hh, ll;
#pragma unroll
        for (int e = 0; e < 4; e++) {
            hh[e] = f2bf(fv[e]);
            ll[e] = f2bf(fv[e] - bf2f(hh[e]));
        }
        *(ushort4v*)&dh[off] = hh;
        *(ushort4v*)&dl[off] = ll;
    }
}

// ---------------------------------------------------------------------------
// Streaming MFMA GEMM body (shared by generic + dual wrappers).
// C[128, N] (+slice partials) = A(bf16 hi/lo) @ W(f32)^T
//   WT: W [N,K] row-major; !WT: W [K,N] row-major.
//   SPLIT: 3-MFMA hi/lo product (~f32 accuracy), W prefetch depth-1.
//   !SPLIT: W prefetch depth-2 (in-flight across barriers).
// BM=128, BN=64, BK=64; 256 thr = 4 waves (2x2), wave tile 64x32.
// Dynamic LDS: split 55296 B, non-split 27648 B.
// ---------------------------------------------------------------------------
template<bool WT, bool SPLIT, bool TANH>
static __device__ __forceinline__ void sgemm_body(
    const unsigned short* __restrict__ Ah, const unsigned short* __restrict__ Al, int lda,
    const float* __restrict__ W, int ldw,
    const float* __restrict__ bias,
    float* __restrict__ C, int ldc, size_t pstride,
    int N, int k_len0, int k_lenB)
{
    extern __shared__ char smem_raw[];
    typedef unsigned short RowT[72];
    RowT* As_h = (RowT*)(smem_raw);            // 128 rows * 144 B = 18432
    RowT* Ws_h = (RowT*)(smem_raw + 18432);    //  64 rows           9216
    RowT* As_l = (RowT*)(smem_raw + 27648);    // split only
    RowT* Ws_l = (RowT*)(smem_raw + 46080);    // split only

    const int t    = threadIdx.x;
    const int lane = t & 63;
    const int wv   = t >> 6;
    const int wr   = wv >> 1;
    const int wc   = wv & 1;
    const int n0   = blockIdx.x * 64;
    const int l15  = lane & 15;
    const int g    = lane >> 4;

    const int y     = blockIdx.y;
    const int k_off = (y == 0) ? 0 : k_len0 + (y - 1) * k_lenB;
    const int k_len = (y == 0) ? k_len0 : k_lenB;
    float* Cp = C + (size_t)y * pstride;

    const int ar = t >> 3;
    const int ac = (t & 7) * 8;
    const int wn = t >> 2, wq = t & 3;
    const int nk = t >> 4, nn4 = (t & 15) * 4;

    f32x4 acc[4][2];
#pragma unroll
    for (int i = 0; i < 4; i++)
#pragma unroll
        for (int j = 0; j < 2; j++) acc[i][j] = (f32x4){0.f, 0.f, 0.f, 0.f};

#define LOAD_A(K0, RA, RAL) do {                                               \
    _Pragma("unroll")                                                          \
    for (int i_ = 0; i_ < 4; i_++)                                             \
        RA[i_] = *(const ushort8*)&Ah[(size_t)(ar + i_ * 32) * lda + (K0) + ac]; \
    if constexpr (SPLIT) {                                                     \
        _Pragma("unroll")                                                      \
        for (int i_ = 0; i_ < 4; i_++)                                         \
            RAL[i_] = *(const ushort8*)&Al[(size_t)(ar + i_ * 32) * lda + (K0) + ac]; \
    }                                                                          \
} while (0)

#define LOAD_W(K0, RW) do {                                                    \
    if constexpr (WT) {                                                        \
        const bool ok_ = (n0 + wn) < N;                                        \
        const float* wb_ = W + (size_t)(n0 + wn) * ldw + (K0);                 \
        _Pragma("unroll")                                                      \
        for (int j_ = 0; j_ < 4; j_++)                                         \
            RW[j_] = ok_ ? *(const float4*)&wb_[j_ * 16 + wq * 4]              \
                         : make_float4(0.f, 0.f, 0.f, 0.f);                    \
    } else {                                                                   \
        _Pragma("unroll")                                                      \
        for (int j_ = 0; j_ < 4; j_++)                                         \
            RW[j_] = *(const float4*)&W[(size_t)((K0) + nk + j_ * 16) * ldw + n0 + nn4]; \
    }                                                                          \
} while (0)

#define STAGE_REGS(RA, RAL, RW) do {                                           \
    _Pragma("unroll")                                                          \
    for (int i_ = 0; i_ < 4; i_++) {                                           \
        *(ushort8*)&As_h[ar + i_ * 32][ac] = RA[i_];                           \
        if constexpr (SPLIT) *(ushort8*)&As_l[ar + i_ * 32][ac] = RAL[i_];     \
    }                                                                          \
    if constexpr (WT) {                                                        \
        _Pragma("unroll")                                                      \
        for (int j_ = 0; j_ < 4; j_++) {                                       \
            const float fv_[4] = {RW[j_].x, RW[j_].y, RW[j_].z, RW[j_].w};     \
            ushort4v hh_, ll_;                                                 \
            _Pragma("unroll")                                                  \
            for (int e_ = 0; e_ < 4; e_++) {                                   \
                hh_[e_] = f2bf(fv_[e_]);                                       \
                if constexpr (SPLIT) ll_[e_] = f2bf(fv_[e_] - bf2f(hh_[e_]));  \
            }                                                                  \
            *(ushort4v*)&Ws_h[wn][j_ * 16 + wq * 4] = hh_;                     \
            if constexpr (SPLIT) *(ushort4v*)&Ws_l[wn][j_ * 16 + wq * 4] = ll_; \
        }                                                                      \
    } else {                                                                   \
        _Pragma("unroll")                                                      \
        for (int j_ = 0; j_ < 4; j_++) {                                       \
            const float fv_[4] = {RW[j_].x, RW[j_].y, RW[j_].z, RW[j_].w};     \
            _Pragma("unroll")                                                  \
            for (int e_ = 0; e_ < 4; e_++) {                                   \
                const unsigned short hb_ = f2bf(fv_[e_]);                      \
                Ws_h[nn4 + e_][nk + j_ * 16] = hb_;                            \
                if constexpr (SPLIT)                                           \
                    Ws_l[nn4 + e_][nk + j_ * 16] = f2bf(fv_[e_] - bf2f(hb_));  \
            }                                                                  \
        }                                                                      \
    }                                                                          \
} while (0)

    const int k_end = k_off + k_len;

    ushort8 ra[4], ral[4], nra[4], nral[4];
    float4 rw0[4], rw1[4], rw2[4];

    LOAD_A(k_off, ra, ral);
    LOAD_W(k_off, rw0);
    if constexpr (!SPLIT) {
        if (k_off + 64 < k_end) LOAD_W(k_off + 64, rw1);
    }

    for (int k0 = k_off; k0 < k_end; k0 += 64) {
        const bool m1 = (k0 + 64) < k_end;
        const bool m2 = (k0 + 128) < k_end;
        if (m1) {
            LOAD_A(k0 + 64, nra, nral);
            if constexpr (SPLIT) LOAD_W(k0 + 64, rw1);
        }

        STAGE_REGS(ra, ral, rw0);
        __syncthreads();

        if constexpr (!SPLIT) {
            if (m2) LOAD_W(k0 + 128, rw2);   // depth-2: in flight across barriers
        }

#pragma unroll
        for (int ks = 0; ks < 2; ks++) {
            const int ko = ks * 32 + g * 8;
            short8 ah[4], bh[2];
#pragma unroll
            for (int mi = 0; mi < 4; mi++)
                ah[mi] = *(const short8*)&As_h[wr * 64 + mi * 16 + l15][ko];
#pragma unroll
            for (int ni = 0; ni < 2; ni++)
                bh[ni] = *(const short8*)&Ws_h[wc * 32 + ni * 16 + l15][ko];
            if constexpr (SPLIT) {
                short8 al[4], bl[2];
#pragma unroll
                for (int mi = 0; mi < 4; mi++)
                    al[mi] = *(const short8*)&As_l[wr * 64 + mi * 16 + l15][ko];
#pragma unroll
                for (int ni = 0; ni < 2; ni++)
                    bl[ni] = *(const short8*)&Ws_l[wc * 32 + ni * 16 + l15][ko];
#pragma unroll
                for (int mi = 0; mi < 4; mi++)
#pragma unroll
                    for (int ni = 0; ni < 2; ni++) {
                        acc[mi][ni] = __builtin_amdgcn_mfma_f32_16x16x32_bf16(ah[mi], bh[ni], acc[mi][ni], 0, 0, 0);
                        acc[mi][ni] = __builtin_amdgcn_mfma_f32_16x16x32_bf16(ah[mi], bl[ni], acc[mi][ni], 0, 0, 0);
                        acc[mi][ni] = __builtin_amdgcn_mfma_f32_16x16x32_bf16(al[mi], bh[ni], acc[mi][ni], 0, 0, 0);
                    }
            } else {
#pragma unroll
                for (int mi = 0; mi < 4; mi++)
#pragma unroll
                    for (int ni = 0; ni < 2; ni++)
                        acc[mi][ni] = __builtin_amdgcn_mfma_f32_16x16x32_bf16(ah[mi], bh[ni], acc[mi][ni], 0, 0, 0);
            }
        }
        __syncthreads();

        if (m1) {
#pragma unroll
            for (int i = 0; i < 4; i++) {
                ra[i] = nra[i];
                if constexpr (SPLIT) ral[i] = nral[i];
            }
#pragma unroll
            for (int j = 0; j < 4; j++) {
                rw0[j] = rw1[j];
                if constexpr (!SPLIT) rw1[j] = rw2[j];
            }
        }
    }
#undef LOAD_A
#undef LOAD_W
#undef STAGE_REGS

#pragma unroll
    for (int mi = 0; mi < 4; mi++) {
#pragma unroll
        for (int ni = 0; ni < 2; ni++) {
            const int col = n0 + wc * 32 + ni * 16 + l15;
            if (col < N) {
                const float bb = bias ? bias[col] : 0.f;
#pragma unroll
                for (int r = 0; r < 4; r++) {
                    const int row = wr * 64 + mi * 16 + g * 4 + r;
                    float v = acc[mi][ni][r] + bb;
                    if (TANH) v = tanhf(v);
                    Cp[(size_t)row * ldc + col] = v;
                }
            }
        }
    }
}

template<bool WT, bool SPLIT, bool TANH>
__global__ __launch_bounds__(256, 2) void sgemm(
    const unsigned short* __restrict__ Ah, const unsigned short* __restrict__ Al, int lda,
    const float* __restrict__ W, int ldw,
    const float* __restrict__ bias,
    float* __restrict__ C, int ldc, size_t pstride,
    int N, int k_len0, int k_lenB)
{
    sgemm_body<WT, SPLIT, TANH>(Ah, Al, lda, W, ldw, bias, C, ldc, pstride, N, k_len0, k_lenB);
}

// Merged gi+gh launch: blockIdx.z selects parameter set.
__global__ __launch_bounds__(256, 2) void gru_gemm(
    const unsigned short* __restrict__ x_hi, const unsigned short* __restrict__ x_lo,
    const float* __restrict__ W_ih,
    const unsigned short* __restrict__ h_hi, const unsigned short* __restrict__ h_lo,
    const float* __restrict__ W_hh,
    float* __restrict__ gi, float* __restrict__ gh)
{
    if (blockIdx.z == 0)
        sgemm_body<true, true, false>(x_hi, x_lo, INDIM, W_ih, INDIM, nullptr,
                                      gi, 3072, (size_t)128 * 3072, 3072, 320, 256);
    else
        sgemm_body<true, true, false>(h_hi, h_lo, H_, W_hh, H_, nullptr,
                                      gh, 3072, (size_t)128 * 3072, 3072, 256, 256);
}

// ---------------------------------------------------------------------------
// GRU gates: sums 4 k-slice partials of gi/gh, adds biases, computes h.
// ---------------------------------------------------------------------------
__global__ __launch_bounds__(256) void gru_gates_kernel(
    const float* __restrict__ gi, const float* __restrict__ gh,
    const float* __restrict__ b_ih, const float* __restrict__ b_hh,
    const float* __restrict__ h_prev,
    float* __restrict__ hid_out,
    unsigned short* __restrict__ cat_hi, unsigned short* __restrict__ cat_lo)
{
    const int id = blockIdx.x * 256 + threadIdx.x;
    const int b = id >> 10, j = id & 1023;
    const size_t base = (size_t)b * 3072 + j;
    float ir = b_ih[j], iz = b_ih[1024 + j], in_ = b_ih[2048 + j];
    float hr = b_hh[j], hz = b_hh[1024 + j], hn = b_hh[2048 + j];
#pragma unroll
    for (int p = 0; p < 4; p++) {
        const float* gp = gi + (size_t)p * (128 * 3072);
        const float* hp = gh + (size_t)p * (128 * 3072);
        ir += gp[base]; iz += gp[base + 1024]; in_ += gp[base + 2048];
        hr += hp[base]; hz += hp[base + 1024]; hn += hp[base + 2048];
    }
    const float r = sigm(ir + hr);
    const float z = sigm(iz + hz);
    const float n = tanhf(in_ + r * hn);
    const float h = (1.f - z) * n + z * h_prev[id];
    hid_out[id] = h;
    const unsigned short hb = f2bf(h);
    cat_hi[(size_t)b * 2048 + j] = hb;
    cat_lo[(size_t)b * 2048 + j] = f2bf(h - bf2f(hb));
}

// ---------------------------------------------------------------------------
// energies (partial over 4 h-slices); 512 thr = 8 waves, 16 l each.
// ---------------------------------------------------------------------------
__global__ __launch_bounds__(512) void energy_partial_kernel(
    const float* __restrict__ qp, const float* __restrict__ enc,
    float* __restrict__ epart)
{
    const int s = blockIdx.x, b = blockIdx.y;
    const int t = threadIdx.x, lane = t & 63, wv = t >> 6;
    __shared__ float q_s[256];
    if (t < 256) {
        const size_t o = (size_t)b * H_ + s * 256 + t;
        q_s[t] = qp[o] + qp[o + 131072] + qp[o + 262144] + qp[o + 393216];
    }
    __syncthreads();
    const float4 qv = *(const float4*)&q_s[lane * 4];
    const float* encb = enc + (size_t)b * H_ + s * 256;
    for (int l0 = 0; l0 < 16; l0++) {
        const int l = wv * 16 + l0;
        float4 ev = *(const float4*)&encb[(size_t)l * (B_ * H_) + lane * 4];
        float p = ev.x * qv.x + ev.y * qv.y + ev.z * qv.z + ev.w * qv.w;
#pragma unroll
        for (int off = 32; off > 0; off >>= 1) p += __shfl_xor(p, off);
        if (lane == 0) epart[((size_t)b * 128 + l) * 4 + s] = p;
    }
}

// ---------------------------------------------------------------------------
// Fused softmax + context: each (s,b) block recomputes softmax from epart
// (cheap, removes a dispatch); s==0 writes attnw output.
// ---------------------------------------------------------------------------
__global__ __launch_bounds__(256) void context_softmax_kernel(
    const float* __restrict__ epart, const float* __restrict__ enc,
    unsigned short* __restrict__ cat_hi, float* __restrict__ attnw)
{
    const int s = blockIdx.x, b = blockIdx.y, t = threadIdx.x;
    const int lane = t & 63, wv = t >> 6;
    __shared__ float w_s[128];
    __shared__ float red[4];

    float e = -INFINITY;
    if (t < 128) {
        float4 pe = *(const float4*)&epart[((size_t)b * 128 + t) * 4];
        e = pe.x + pe.y + pe.z + pe.w;
    }
    float mx = e;
#pragma unroll
    for (int off = 32; off > 0; off >>= 1) mx = fmaxf(mx, __shfl_xor(mx, off));
    if (lane == 0) red[wv] = mx;
    __syncthreads();
    const float gm = fmaxf(fmaxf(red[0], red[1]), fmaxf(red[2], red[3]));
    __syncthreads();
    float ex = (t < 128) ? __expf(e - gm) : 0.f;
    float sm = ex;
#pragma unroll
    for (int off = 32; off > 0; off >>= 1) sm += __shfl_xor(sm, off);
    if (lane == 0) red[wv] = sm;
    __syncthreads();
    const float gs = red[0] + red[1] + red[2] + red[3];
    if (t < 128) {
        const float w = ex / gs;
        w_s[t] = w;
        if (s == 0) attnw[(size_t)b * L_ + t] = w;
    }
    __syncthreads();

    const int h = s * 256 + t;
    const float* encb = enc + (size_t)b * H_ + h;
    float c = 0.f;
#pragma unroll 4
    for (int l = 0; l < 128; l++)
        c += w_s[l] * encb[(size_t)l * (B_ * H_)];
    cat_hi[(size_t)b * 2048 + 1024 + h] = f2bf(c);
}

// co = tanh(sum of 4 partials + b_cat) -> bf16
__global__ __launch_bounds__(256) void co_reduce_kernel(
    const float* __restrict__ co_part, const float* __restrict__ b_cat,
    unsigned short* __restrict__ co_hi)
{
    const int id = blockIdx.x * 256 + threadIdx.x;
    const int j = id & 1023;
    float s = b_cat[j];
#pragma unroll
    for (int p = 0; p < 4; p++) s += co_part[(size_t)p * 131072 + id];
    co_hi[id] = f2bf(tanhf(s));
}

// ---------------------------------------------------------------------------
extern "C" void kernel_launch(void* const* d_in, const int* in_sizes, int n_in,
                              void* d_out, int out_size, void* d_ws, size_t ws_size,
                              hipStream_t stream)
{
    const int*   seq    = (const int*)  d_in[0];
    const float* lh     = (const float*)d_in[1];
    const float* enc    = (const float*)d_in[2];
    const int*   c2n    = (const int*)  d_in[3];
    const int*   c2f    = (const int*)  d_in[4];
    const float* emb    = (const float*)d_in[5];
    const float* semb   = (const float*)d_in[6];
    const float* nemb   = (const float*)d_in[7];
    const float* W_ih   = (const float*)d_in[8];
    const float* W_hh   = (const float*)d_in[9];
    const float* b_ih   = (const float*)d_in[10];
    const float* b_hh   = (const float*)d_in[11];
    const float* W_attn = (const float*)d_in[12];
    // d_in[13] = b_attn: dropped (softmax shift-invariant, exact)
    const float* W_cat  = (const float*)d_in[14];
    const float* b_cat  = (const float*)d_in[15];
    const float* W_out  = (const float*)d_in[16];
    const float* b_out  = (const float*)d_in[17];

    float* out    = (float*)d_out;
    float* hidden = out + (size_t)B_ * V_;
    float* attnw  = hidden + (size_t)B_ * H_;

    // ---- workspace layout ----
    unsigned short* x_hi   = (unsigned short*)d_ws;            // 128*1088
    unsigned short* x_lo   = x_hi   + (size_t)128 * INDIM;
    unsigned short* h_hi   = x_lo   + (size_t)128 * INDIM;     // 128*1024
    unsigned short* h_lo   = h_hi   + (size_t)128 * 1024;
    unsigned short* cat_hi = h_lo   + (size_t)128 * 1024;      // 128*2048
    unsigned short* cat_lo = cat_hi + (size_t)128 * 2048;
    unsigned short* co_hi  = cat_lo + (size_t)128 * 2048;      // 128*1024
    float* fbase   = (float*)(co_hi + (size_t)128 * 1024);
    float* gi_part = fbase;                                    // 4*128*3072
    float* gh_part = gi_part + (size_t)4 * 128 * 3072;         // 4*128*3072
    // aliases (gi/gh dead after gates):
    float* q_part  = fbase;                                    // 4*128*1024
    float* co_part = q_part + (size_t)4 * 128 * 1024;          // 4*128*1024
    float* epart   = co_part + (size_t)4 * 128 * 1024;         // 128*128*4

    const int SMEM_SPLIT = 55296;
    const int SMEM_PLAIN = 27648;

    // 1. prep: x, h bf16 hi/lo planes
    hipLaunchKernelGGL(prep_kernel, dim3(B_), dim3(256), 0, stream,
                       seq, c2n, c2f, emb, semb, nemb, lh, x_hi, x_lo, h_hi, h_lo);
    // 2+3. gi & gh partials in one dispatch (z selects)
    hipLaunchKernelGGL(gru_gemm, dim3(48, 4, 2), dim3(256), SMEM_SPLIT, stream,
                       x_hi, x_lo, W_ih, h_hi, h_lo, W_hh, gi_part, gh_part);
    // 4. gates -> hidden + cat planes
    hipLaunchKernelGGL(gru_gates_kernel, dim3(512), dim3(256), 0, stream,
                       gi_part, gh_part, b_ih, b_hh, lh, hidden, cat_hi, cat_lo);
    // 5. q partials = h @ W_attn (NT, split): K=1024 -> 4 x 256
    hipLaunchKernelGGL((sgemm<false, true, false>), dim3(16, 4), dim3(256), SMEM_SPLIT, stream,
                       cat_hi, cat_lo, 2048, W_attn, H_, (const float*)nullptr,
                       q_part, H_, (size_t)128 * 1024, H_, 256, 256);
    // 6. energies
    hipLaunchKernelGGL(energy_partial_kernel, dim3(4, 128), dim3(512), 0, stream,
                       q_part, enc, epart);
    // 7. softmax + context fused
    hipLaunchKernelGGL(context_softmax_kernel, dim3(4, 128), dim3(256), 0, stream,
                       epart, enc, cat_hi, attnw);
    // 8. co partials = cat @ W_cat.T: K=2048 -> 4 x 512
    hipLaunchKernelGGL((sgemm<true, false, false>), dim3(16, 4), dim3(256), SMEM_PLAIN, stream,
                       cat_hi, cat_hi, 2048, W_cat, 2048, (const float*)nullptr,
                       co_part, H_, (size_t)128 * 1024, H_, 512, 512);
    // 9. co = tanh(sum + b_cat) -> bf16
    hipLaunchKernelGGL(co_reduce_kernel, dim3(512), dim3(256), 0, stream,
                       co_part, b_cat, co_hi);
    // 10. out = co @ W_out.T + b_out (depth-2 W prefetch)
    hipLaunchKernelGGL((sgemm<true, false, false>), dim3((V_ + 63) / 64, 1), dim3(256), SMEM_PLAIN, stream,
                       co_hi, co_hi, H_, W_out, H_, b_out,
                       out, V_, (size_t)0, V_, H_, H_);
}